// Round 20
// baseline (209.344 us; speedup 1.0000x reference)
//
#include <hip/hip_runtime.h>
#include <hip/hip_bf16.h>

// SAGAN attention block: B=4, C=256, H=W=64 (N=4096).
// Round 20 = r19 with the occupancy lever unblocked: r18 cut attn to 88 arch
// VGPRs (152 unified <= 170 => 3 waves/SIMD permitted) -- LDS was the binding
// constraint. Single-buffer V (K stays dbuf): 64->48KB/block => 3 blocks/CU.
// Key-split x4 (1024 blocks) so 3/CU is actually populated. Schedule: 2
// barriers x 32 iters = same 64 barriers as r19's 1x64. Merge x4 as separate
// kernel (r11-proven); conv_out reverts to simple r16 form reading merged OT.

typedef short short8 __attribute__((ext_vector_type(8)));
typedef short short4v __attribute__((ext_vector_type(4)));
typedef float f32x4 __attribute__((ext_vector_type(4)));
typedef _Float16 f16x8 __attribute__((ext_vector_type(8)));
typedef unsigned short u16;
typedef unsigned int u32;

#define DEV static __device__ __forceinline__
#define MFMA16(a, b, c) __builtin_amdgcn_mfma_f32_16x16x32_f16(a, b, c, 0, 0, 0)

DEV u16 h16(float x) {
    union { _Float16 h; u16 u; } c;
    c.h = (_Float16)x;
    return c.u;
}
DEV f16x8 ldh8(const u16* p) { return *reinterpret_cast<const f16x8*>(p); }

DEV u32 cvtpk(float a, float b) {  // packed f16 (rtz): lo=a, hi=b
    u32 r;
    asm("v_cvt_pkrtz_f16_f32 %0, %1, %2" : "=v"(r) : "v"(a), "v"(b));
    return r;
}

// async global->LDS, 16B per lane; dst is wave-uniform base, HW adds lane*16
DEV void gload16(const void* g, void* l) {
    __builtin_amdgcn_global_load_lds(
        (const __attribute__((address_space(1))) unsigned int*)g,
        (__attribute__((address_space(3))) unsigned int*)l, 16, 0, 0);
}

// ---- workspace byte offsets ----
constexpr size_t OFF_WH = 0;          // 128K fp16
constexpr size_t OFF_WV = 131072;     // 128K fp16
constexpr size_t OFF_MB = 262144;     // 1K f32 (bias vector b = Wf^T bg)
constexpr size_t OFF_ML = 266240;     // 512K f32 pairs (4 splits x 16384 x {m,l})
constexpr size_t OFF_M  = 790528;     // 128K fp16 (M = Wf^T Wg)
constexpr size_t OFF_U  = 1310720;    // 8M fp16 [m][c]  (Q source: u; dead after attn)
constexpr size_t OFF_H  = OFF_U + 8388608;    // 8M fp16 [b][c][n] (V, keys permuted per 32-block)
constexpr size_t OFF_XT = OFF_H + 8388608;    // 8M fp16 [m][c]  (x; attention K source)
constexpr size_t OFF_OP = OFF_XT + 8388608;   // 32M fp16 (4 splits)
constexpr size_t OFF_OT = OFF_U;              // 8M fp16, aliases dead U
// high-water mark = OFF_OP + 33554432 = 60,030,976 bytes (round-2/5/11-proven)

// ---------------- M = Wf^T Wg (+Mb); also converts Wh,Wv rows to fp16 ----------------
__global__ __launch_bounds__(256) void k_gemm_M(
    const float* __restrict__ Wf, const float* __restrict__ Wg,
    const float* __restrict__ bg, const float* __restrict__ Wh,
    const float* __restrict__ Wv,
    u16* __restrict__ M, float* __restrict__ Mb, u16* WH, u16* WV) {
    int c = blockIdx.x;       // row of M (and of Wh/Wv to convert)
    int t = threadIdx.x;      // col
    size_t rowi = (size_t)c * 256 + t;
    WH[rowi] = h16(Wh[rowi]);
    WV[rowi] = h16(Wv[rowi]);
    __shared__ float wf[256];
    wf[t] = Wf[(size_t)t * 256 + c];  // Wf[o=t][c]
    __syncthreads();
    float acc = 0.f;
    for (int o = 0; o < 256; ++o) acc += wf[o] * Wg[(size_t)o * 256 + t];
    M[rowi] = h16(acc);
    if (t == 0) {
        float s = 0.f;
        for (int o = 0; o < 256; ++o) s += wf[o] * bg[o];
        Mb[c] = s;
    }
}

// ---------------- fused prep: x -> Xt (global+LDS), then U and H from LDS ----------------
__global__ __launch_bounds__(256) void k_prep(
    const float* __restrict__ x, const u16* __restrict__ M,
    const float* __restrict__ Mb, const u16* __restrict__ WH,
    const float* __restrict__ bh,
    u16* __restrict__ Xt, u16* __restrict__ U, u16* __restrict__ Hb) {
    __shared__ float tbuf[64][65];   // transpose scratch (f32)
    __shared__ u16 xt[64][264];      // row-padded fp16 tile (stride 528B)

    int bid = blockIdx.x;            // 256 blocks: 64-row stripes of m
    int m0 = bid * 64;
    int b = m0 >> 12, n0 = m0 & 4095;
    int tid = threadIdx.x;
    int tx = tid & 63, ty = tid >> 6;
    int nl = tid >> 2, cg = tid & 3;

    // ---- phase 1: transpose x[b][c][n0..63] -> xt LDS tile + XT global ----
    for (int ct4 = 0; ct4 < 4; ++ct4) {
        const float* src = x + ((size_t)(b * 256 + ct4 * 64)) * 4096 + n0;
#pragma unroll
        for (int k = 0; k < 16; ++k) {
            int cl = ty * 16 + k;
            tbuf[cl][tx] = src[(size_t)cl * 4096 + tx];
        }
        __syncthreads();
        short8 h0, h1;
#pragma unroll
        for (int j = 0; j < 8; ++j) h0[j] = (short)h16(tbuf[cg * 16 + j][nl]);
#pragma unroll
        for (int j = 8; j < 16; ++j) h1[j - 8] = (short)h16(tbuf[cg * 16 + j][nl]);
        int colbase = ct4 * 64 + cg * 16;
        *reinterpret_cast<short8*>(&xt[nl][colbase]) = h0;
        *reinterpret_cast<short8*>(&xt[nl][colbase + 8]) = h1;
        size_t dst = ((size_t)(m0 + nl)) * 256 + colbase;
        *reinterpret_cast<short8*>(Xt + dst) = h0;
        *reinterpret_cast<short8*>(Xt + dst + 8) = h1;
        __syncthreads();
    }

    // ---- phase 2: U[m][o] and H[o][n] from the LDS tile ----
    int w = tid >> 6, lane = tid & 63, r = lane & 15, g = lane >> 4;
    f16x8 A[8];
#pragma unroll
    for (int ks = 0; ks < 8; ++ks)
        A[ks] = *reinterpret_cast<const f16x8*>(&xt[w * 16 + r][ks * 32 + 8 * g]);

#pragma unroll 4
    for (int ot = 0; ot < 16; ++ot) {
        f32x4 au = {0.f, 0.f, 0.f, 0.f};
        f32x4 ah = {0.f, 0.f, 0.f, 0.f};
        const u16* mrow = M + (size_t)(ot * 16 + r) * 256;
        const u16* hrow = WH + (size_t)(ot * 16 + r) * 256;
#pragma unroll
        for (int ks = 0; ks < 8; ++ks) {
            int k0 = ks * 32 + 8 * g;
            au = MFMA16(A[ks], ldh8(mrow + k0), au);
            ah = MFMA16(A[ks], ldh8(hrow + k0), ah);
        }
        int o = ot * 16 + r;
        float mb = Mb[o];
        float bhv = bh[o];
#pragma unroll
        for (int q = 0; q < 4; ++q) {
            int rloc = w * 16 + 4 * g + q;
            U[(size_t)(m0 + rloc) * 256 + o] = h16(au[q] + mb);
            int n = n0 + rloc;
            int k5 = n & 31;
            int kp = (k5 < 16) ? (8 * (k5 >> 2) + (k5 & 3))
                               : (8 * ((k5 - 16) >> 2) + 4 + (k5 & 3));
            int np = (n & ~31) | kp;
            Hb[((size_t)(b * 256 + o)) * 4096 + np] = h16(ah[q] + bhv);
        }
    }
}

// ---------------- flash attention: K dbuf + V single-buffer (48KB), split x4 ----------------
__global__ __launch_bounds__(256) void k_attn(
    const u16* __restrict__ F, const u16* __restrict__ G,
    const u16* __restrict__ Hb, u16* __restrict__ OP, float* __restrict__ ML) {
    // K tile [32 keys][256 c] fp16, 16KB x2, swizzle byte ^= (row&7)<<4.
    // V tile paired-row 16KB single-buffered (staged at top of iter, drained
    // at midbar -- PV(it-1) reads finished at the previous end-barrier).
    __shared__ u16 Kd[2][8192];
    __shared__ u16 Vd[8192];

    int bid = blockIdx.x;            // 1024 = 8 xcd * 128; 3 blocks/CU capacity
    int xcd = bid & 7, idx = bid >> 3;
    int b = xcd >> 1;                // batch
    int ks = ((idx & 1) << 1) | (xcd & 1);  // key-quarter 0..3
    int qb = idx >> 1;               // 0..63
    int tid = threadIdx.x;
    int w = tid >> 6, lane = tid & 63, r = lane & 15, g = lane >> 4;
    int j0 = qb * 64 + w * 16;       // wave's 16 queries
    const float L2E = 1.4426950408889634f;

    int vlc = (r >> 1) * 128 + (((16 * g) + (r & 1) * 64) ^ (((r >> 1) & 7) << 4));

    f16x8 Qf[8];
    {
        const u16* q = G + (size_t)(b * 4096 + j0 + r) * 256;
#pragma unroll
        for (int k = 0; k < 8; ++k) Qf[k] = ldh8(q + k * 32 + 8 * g);
    }
    f32x4 O[16];
#pragma unroll
    for (int i = 0; i < 16; ++i) O[i] = {0.f, 0.f, 0.f, 0.f};
    float m = -1e30f, l = 0.f;

    const char* Fb  = (const char*)(F + (size_t)b * 4096 * 256);
    const char* Hbb = (const char*)(Hb + (size_t)b * 256 * 4096);

    int ksrc[4], vsrc[4];
#pragma unroll
    for (int t = 0; t < 4; ++t) {
        int d = (w * 4 + t) * 1024 + lane * 16;
        int row = d >> 9, col = d & 511;
        ksrc[t] = row * 512 + (col ^ ((row & 7) << 4));
        int r128 = d >> 7, wn = d & 127;
        int wp = wn ^ ((r128 & 7) << 4);
        vsrc[t] = ((r128 * 2 + (wp >> 6)) << 13) + (wp & 63);
    }

#define STAGE_K(bufn, I0)                                                       \
    do {                                                                        \
        const char* kb_ = Fb + (size_t)(I0) * 512;                              \
        char* kl = (char*)Kd[bufn];                                             \
        _Pragma("unroll") for (int t = 0; t < 4; ++t)                           \
            gload16(kb_ + ksrc[t], kl + (w * 4 + t) * 1024);                    \
    } while (0)
#define STAGE_V(I0)                                                             \
    do {                                                                        \
        const char* vb_ = Hbb + (size_t)(I0) * 2;                               \
        char* vl = (char*)Vd;                                                   \
        _Pragma("unroll") for (int t = 0; t < 4; ++t)                           \
            gload16(vb_ + vsrc[t], vl + (w * 4 + t) * 1024);                    \
    } while (0)

    int i0beg = ks * 1024;
    STAGE_K(0, i0beg);
    STAGE_V(i0beg);
    __syncthreads();   // drains vmcnt(0): K0 + V0 ready

    for (int it = 0; it < 32; ++it) {
        int cur = it & 1;
        if (it > 0) STAGE_V(i0beg + it * 32);              // V for THIS iter
        if (it + 1 < 32) STAGE_K(cur ^ 1, i0beg + (it + 1) * 32);

        const char* Kl = (const char*)Kd[cur];

        // ---- QK^T swapped: A = K (rows = keys), B = Q ----
        f32x4 s0 = {0.f, 0.f, 0.f, 0.f};
        f32x4 s1 = {0.f, 0.f, 0.f, 0.f};
        __builtin_amdgcn_s_setprio(1);
        {
            const char* kr = Kl + r * 512;
            int sw = (r & 7) << 4;
#pragma unroll
            for (int k = 0; k < 8; ++k) {
                f16x8 ka = *reinterpret_cast<const f16x8*>(kr + ((k * 64 + 16 * g) ^ sw));
                s0 = MFMA16(ka, Qf[k], s0);
            }
        }
        {
            const char* kr = Kl + (16 + r) * 512;
            int sw = (r & 7) << 4;
#pragma unroll
            for (int k = 0; k < 8; ++k) {
                f16x8 ka = *reinterpret_cast<const f16x8*>(kr + ((k * 64 + 16 * g) ^ sw));
                s1 = MFMA16(ka, Qf[k], s1);
            }
        }
        __builtin_amdgcn_s_setprio(0);

        // ---- softmax: shuffle-free common path (r18) ----
        float v = fmaxf(fmaxf(fmaxf(s0[0], s0[1]), fmaxf(s0[2], s0[3])),
                        fmaxf(fmaxf(s1[0], s1[1]), fmaxf(s1[2], s1[3])));
        if (!__all(v - m <= 8.0f)) {  // rare: full per-query max + rescale
            v = fmaxf(v, __shfl_xor(v, 16));
            v = fmaxf(v, __shfl_xor(v, 32));
            float mn = fmaxf(m, v);
            float corr = exp2f((m - mn) * L2E);
            m = mn;
            l *= corr;
#pragma unroll
            for (int ct = 0; ct < 16; ++ct) O[ct] *= corr;
        }
#pragma unroll
        for (int q = 0; q < 4; ++q) {
            s0[q] = exp2f((s0[q] - m) * L2E);
            s1[q] = exp2f((s1[q] - m) * L2E);
        }
        l += (s0[0] + s0[1] + s0[2] + s0[3]) + (s1[0] + s1[1] + s1[2] + s1[3]);

        union { u32 wd[4]; f16x8 fr; } pu;
        pu.wd[0] = cvtpk(s0[0], s0[1]);
        pu.wd[1] = cvtpk(s0[2], s0[3]);
        pu.wd[2] = cvtpk(s1[0], s1[1]);
        pu.wd[3] = cvtpk(s1[2], s1[3]);

        __syncthreads();   // midbar: V(it) (and K(it+1)) landed

        // ---- PV: O[c][j] += V[c][slot] * P[slot][j] ----
        const char* Vb = (const char*)Vd + vlc;
        __builtin_amdgcn_s_setprio(1);
#pragma unroll
        for (int ct = 0; ct < 16; ++ct) {
            f16x8 vb = *reinterpret_cast<const f16x8*>(Vb + ct * 1024);
            O[ct] = MFMA16(vb, pu.fr, O[ct]);
        }
        __builtin_amdgcn_s_setprio(0);

        __syncthreads();   // endbar: PV reads done -> next STAGE_V may overwrite
    }
#undef STAGE_K
#undef STAGE_V

    l += __shfl_xor(l, 16);
    l += __shfl_xor(l, 32);
    float inv = 1.f / l;
    size_t mrow = (size_t)ks * 16384 + b * 4096 + j0 + r;
#pragma unroll
    for (int ct = 0; ct < 16; ++ct) {
        short4v pk;
#pragma unroll
        for (int q = 0; q < 4; ++q) pk[q] = (short)h16(O[ct][q] * inv);
        *reinterpret_cast<short4v*>(OP + mrow * 256 + ct * 16 + 4 * g) = pk;
    }
    if (g == 0) {
        size_t mi = mrow * 2;
        ML[mi] = m;
        ML[mi + 1] = l;
    }
}

// ---------------- merge key-splits (x4, normalized partials) -> OT fp16 [m][c] ----------------
__global__ __launch_bounds__(256) void k_merge(
    const u16* __restrict__ OP, const float* __restrict__ ML, u16* __restrict__ OT) {
    int t = blockIdx.x * 256 + threadIdx.x;  // 524288 threads
    int m = t >> 5;
    int c0 = (t & 31) * 8;
    const float L2E = 1.4426950408889634f;
    float mm[4], ll[4];
    float M = -1e30f;
#pragma unroll
    for (int ks = 0; ks < 4; ++ks) {
        size_t mi = ((size_t)ks * 16384 + m) * 2;
        mm[ks] = ML[mi];
        ll[ks] = ML[mi + 1];
        M = fmaxf(M, mm[ks]);
    }
    float wl[4], L = 0.f;
#pragma unroll
    for (int ks = 0; ks < 4; ++ks) {
        wl[ks] = exp2f((mm[ks] - M) * L2E) * ll[ks];
        L += wl[ks];
    }
    float inv = 1.f / L;
    float acc[8];
#pragma unroll
    for (int j = 0; j < 8; ++j) acc[j] = 0.f;
#pragma unroll
    for (int ks = 0; ks < 4; ++ks) {
        f16x8 v = ldh8(OP + ((size_t)ks * 16384 + m) * 256 + c0);
#pragma unroll
        for (int j = 0; j < 8; ++j) acc[j] += wl[ks] * (float)v[j];
    }
    short8 outp;
#pragma unroll
    for (int j = 0; j < 8; ++j) outp[j] = (short)h16(acc[j] * inv);
    *reinterpret_cast<short8*>(OT + (size_t)m * 256 + c0) = outp;
}

// ---------------- final conv: fp16 MFMA, f32 out ----------------
__global__ __launch_bounds__(256) void k_conv_out(
    const u16* __restrict__ WV, const u16* __restrict__ OT,
    const float* __restrict__ bv, float* __restrict__ out) {
    int bidn = blockIdx.x & 255, bido = blockIdx.x >> 8;
    int w = threadIdx.x >> 6, lane = threadIdx.x & 63, r = lane & 15, g = lane >> 4;
    int o0 = bido * 64 + w * 16, n0 = bidn * 64;
    f32x4 acc[4];
#pragma unroll
    for (int i = 0; i < 4; ++i) acc[i] = {0.f, 0.f, 0.f, 0.f};
    const u16* arow = WV + (size_t)(o0 + r) * 256;
#pragma unroll
    for (int ks = 0; ks < 8; ++ks) {
        int k0 = ks * 32 + 8 * g;
        f16x8 a = ldh8(arow + k0);
#pragma unroll
        for (int ntl = 0; ntl < 4; ++ntl) {
            f16x8 bb = ldh8(OT + (size_t)(n0 + ntl * 16 + r) * 256 + k0);
            acc[ntl] = MFMA16(a, bb, acc[ntl]);
        }
    }
#pragma unroll
    for (int ntl = 0; ntl < 4; ++ntl) {
#pragma unroll
        for (int q = 0; q < 4; ++q) {
            int o = o0 + 4 * g + q;
            int nf = n0 + ntl * 16 + r;
            int bb = nf >> 12, n = nf & 4095;
            out[((size_t)(bb * 256 + o)) * 4096 + n] = acc[ntl][q] + bv[o];
        }
    }
}

extern "C" void kernel_launch(void* const* d_in, const int* in_sizes, int n_in,
                              void* d_out, int out_size, void* d_ws, size_t ws_size,
                              hipStream_t stream) {
    const float* x  = (const float*)d_in[0];
    const float* Wf = (const float*)d_in[1];
    const float* bf = (const float*)d_in[2];  // cancels in softmax (const in i)
    const float* Wg = (const float*)d_in[3];
    const float* bg = (const float*)d_in[4];
    const float* Wh = (const float*)d_in[5];
    const float* bh = (const float*)d_in[6];
    const float* Wv = (const float*)d_in[7];
    const float* bv = (const float*)d_in[8];
    float* out = (float*)d_out;
    char* ws = (char*)d_ws;
    (void)bf;

    u16* WH = (u16*)(ws + OFF_WH);
    u16* WV = (u16*)(ws + OFF_WV);
    float* MB = (float*)(ws + OFF_MB);
    float* ML = (float*)(ws + OFF_ML);
    u16* M  = (u16*)(ws + OFF_M);
    u16* U  = (u16*)(ws + OFF_U);
    u16* H  = (u16*)(ws + OFF_H);
    u16* XT = (u16*)(ws + OFF_XT);
    u16* OP = (u16*)(ws + OFF_OP);
    u16* OT = (u16*)(ws + OFF_OT);   // aliases U (dead after attn)

    k_gemm_M<<<256, 256, 0, stream>>>(Wf, Wg, bg, Wh, Wv, M, MB, WH, WV);
    k_prep<<<256, 256, 0, stream>>>(x, M, MB, WH, bh, XT, U, H);
    k_attn<<<1024, 256, 0, stream>>>(XT, U, H, OP, ML);  // K = Xt, Q = U
    k_merge<<<2048, 256, 0, stream>>>(OP, ML, OT);
    k_conv_out<<<1024, 256, 0, stream>>>(WV, OT, bv, out);
}

// Round 21
// 204.218 us; speedup vs baseline: 1.0251x; 1.0251x over previous
//
#include <hip/hip_runtime.h>
#include <hip/hip_bf16.h>

// SAGAN attention block: B=4, C=256, H=W=64 (N=4096).
// Round 21 = byte-for-byte revert to round 19 (best proven: 204.7us total,
// attn 128us, absmax 0.0078). r20's occupancy attempt (V single-buffer, 48KB)
// raised arch VGPRs 88->116 => 180 unified > 170 => still 2 waves/SIMD, plus
// midbar overhead => attn 144us. Fourth confirmation the occupancy lever is
// register-blocked; the (regs<=170, LDS<=53KB) window is unreachable here.

typedef short short8 __attribute__((ext_vector_type(8)));
typedef short short4v __attribute__((ext_vector_type(4)));
typedef float f32x4 __attribute__((ext_vector_type(4)));
typedef _Float16 f16x8 __attribute__((ext_vector_type(8)));
typedef unsigned short u16;
typedef unsigned int u32;

#define DEV static __device__ __forceinline__
#define MFMA16(a, b, c) __builtin_amdgcn_mfma_f32_16x16x32_f16(a, b, c, 0, 0, 0)

DEV u16 h16(float x) {
    union { _Float16 h; u16 u; } c;
    c.h = (_Float16)x;
    return c.u;
}
DEV f16x8 ldh8(const u16* p) { return *reinterpret_cast<const f16x8*>(p); }

DEV u32 cvtpk(float a, float b) {  // packed f16 (rtz): lo=a, hi=b
    u32 r;
    asm("v_cvt_pkrtz_f16_f32 %0, %1, %2" : "=v"(r) : "v"(a), "v"(b));
    return r;
}

// async global->LDS, 16B per lane; dst is wave-uniform base, HW adds lane*16
DEV void gload16(const void* g, void* l) {
    __builtin_amdgcn_global_load_lds(
        (const __attribute__((address_space(1))) unsigned int*)g,
        (__attribute__((address_space(3))) unsigned int*)l, 16, 0, 0);
}

// ---- workspace byte offsets ----
constexpr size_t OFF_WH = 0;          // 128K fp16
constexpr size_t OFF_WV = 131072;     // 128K fp16
constexpr size_t OFF_MB = 262144;     // 1K f32 (bias vector b = Wf^T bg)
constexpr size_t OFF_ML = 266240;     // 256K f32 pairs (2 splits x 16384 x {m,l})
constexpr size_t OFF_M  = 524288;     // 128K fp16 (M = Wf^T Wg)
constexpr size_t OFF_U  = 1310720;    // 8M fp16 [m][c]  (Q source: u)
constexpr size_t OFF_H  = OFF_U + 8388608;    // 8M fp16 [b][c][n] (V, keys permuted per 32-block)
constexpr size_t OFF_XT = OFF_H + 8388608;    // 8M fp16 [m][c]  (x; ALSO the attention K source)
constexpr size_t OFF_OP = OFF_XT + 8388608;   // 16M fp16 (2 splits)
// high-water mark = OFF_OP + 16777216 = 43,253,760 bytes

// ---------------- M = Wf^T Wg (+Mb); also converts Wh,Wv rows to fp16 ----------------
__global__ __launch_bounds__(256) void k_gemm_M(
    const float* __restrict__ Wf, const float* __restrict__ Wg,
    const float* __restrict__ bg, const float* __restrict__ Wh,
    const float* __restrict__ Wv,
    u16* __restrict__ M, float* __restrict__ Mb, u16* WH, u16* WV) {
    int c = blockIdx.x;       // row of M (and of Wh/Wv to convert)
    int t = threadIdx.x;      // col
    size_t rowi = (size_t)c * 256 + t;
    WH[rowi] = h16(Wh[rowi]);
    WV[rowi] = h16(Wv[rowi]);
    __shared__ float wf[256];
    wf[t] = Wf[(size_t)t * 256 + c];  // Wf[o=t][c]
    __syncthreads();
    float acc = 0.f;
    for (int o = 0; o < 256; ++o) acc += wf[o] * Wg[(size_t)o * 256 + t];
    M[rowi] = h16(acc);
    if (t == 0) {
        float s = 0.f;
        for (int o = 0; o < 256; ++o) s += wf[o] * bg[o];
        Mb[c] = s;
    }
}

// ---------------- fused prep: x -> Xt (global+LDS), then U and H from LDS ----------------
__global__ __launch_bounds__(256) void k_prep(
    const float* __restrict__ x, const u16* __restrict__ M,
    const float* __restrict__ Mb, const u16* __restrict__ WH,
    const float* __restrict__ bh,
    u16* __restrict__ Xt, u16* __restrict__ U, u16* __restrict__ Hb) {
    __shared__ float tbuf[64][65];   // transpose scratch (f32)
    __shared__ u16 xt[64][264];      // row-padded fp16 tile (stride 528B)

    int bid = blockIdx.x;            // 256 blocks: 64-row stripes of m
    int m0 = bid * 64;
    int b = m0 >> 12, n0 = m0 & 4095;
    int tid = threadIdx.x;
    int tx = tid & 63, ty = tid >> 6;
    int nl = tid >> 2, cg = tid & 3;

    // ---- phase 1: transpose x[b][c][n0..63] -> xt LDS tile + XT global ----
    for (int ct4 = 0; ct4 < 4; ++ct4) {
        const float* src = x + ((size_t)(b * 256 + ct4 * 64)) * 4096 + n0;
#pragma unroll
        for (int k = 0; k < 16; ++k) {
            int cl = ty * 16 + k;
            tbuf[cl][tx] = src[(size_t)cl * 4096 + tx];
        }
        __syncthreads();
        short8 h0, h1;
#pragma unroll
        for (int j = 0; j < 8; ++j) h0[j] = (short)h16(tbuf[cg * 16 + j][nl]);
#pragma unroll
        for (int j = 8; j < 16; ++j) h1[j - 8] = (short)h16(tbuf[cg * 16 + j][nl]);
        int colbase = ct4 * 64 + cg * 16;
        *reinterpret_cast<short8*>(&xt[nl][colbase]) = h0;
        *reinterpret_cast<short8*>(&xt[nl][colbase + 8]) = h1;
        size_t dst = ((size_t)(m0 + nl)) * 256 + colbase;
        *reinterpret_cast<short8*>(Xt + dst) = h0;
        *reinterpret_cast<short8*>(Xt + dst + 8) = h1;
        __syncthreads();
    }

    // ---- phase 2: U[m][o] and H[o][n] from the LDS tile ----
    int w = tid >> 6, lane = tid & 63, r = lane & 15, g = lane >> 4;
    f16x8 A[8];
#pragma unroll
    for (int ks = 0; ks < 8; ++ks)
        A[ks] = *reinterpret_cast<const f16x8*>(&xt[w * 16 + r][ks * 32 + 8 * g]);

#pragma unroll 4
    for (int ot = 0; ot < 16; ++ot) {
        f32x4 au = {0.f, 0.f, 0.f, 0.f};
        f32x4 ah = {0.f, 0.f, 0.f, 0.f};
        const u16* mrow = M + (size_t)(ot * 16 + r) * 256;
        const u16* hrow = WH + (size_t)(ot * 16 + r) * 256;
#pragma unroll
        for (int ks = 0; ks < 8; ++ks) {
            int k0 = ks * 32 + 8 * g;
            au = MFMA16(A[ks], ldh8(mrow + k0), au);
            ah = MFMA16(A[ks], ldh8(hrow + k0), ah);
        }
        int o = ot * 16 + r;
        float mb = Mb[o];
        float bhv = bh[o];
#pragma unroll
        for (int q = 0; q < 4; ++q) {
            int rloc = w * 16 + 4 * g + q;
            U[(size_t)(m0 + rloc) * 256 + o] = h16(au[q] + mb);
            int n = n0 + rloc;
            int k5 = n & 31;
            int kp = (k5 < 16) ? (8 * (k5 >> 2) + (k5 & 3))
                               : (8 * ((k5 - 16) >> 2) + 4 + (k5 & 3));
            int np = (n & ~31) | kp;
            Hb[((size_t)(b * 256 + o)) * 4096 + np] = h16(ah[q] + bhv);
        }
    }
}

// ---------------- flash attention: swapped-QK 16x16, lane-local P (K=Xt, Q=U) ----------------
__global__ __launch_bounds__(256, 2) void k_attn(
    const u16* __restrict__ F, const u16* __restrict__ G,
    const u16* __restrict__ Hb, u16* __restrict__ OP, float* __restrict__ ML) {
    __shared__ u16 Kd[2][8192];
    __shared__ u16 Vd[2][8192];

    int bid = blockIdx.x;            // 512 = 8 xcd * 64; 2 blocks/CU
    int xcd = bid & 7, idx = bid >> 3;
    int b = xcd >> 1, ks = xcd & 1;  // XCD carries (batch, key-half)
    int tid = threadIdx.x;
    int w = tid >> 6, lane = tid & 63, r = lane & 15, g = lane >> 4;
    int j0 = idx * 64 + w * 16;      // wave's 16 queries
    const float L2E = 1.4426950408889634f;

    int vlc = (r >> 1) * 128 + (((16 * g) + (r & 1) * 64) ^ (((r >> 1) & 7) << 4));

    f16x8 Qf[8];
    {
        const u16* q = G + (size_t)(b * 4096 + j0 + r) * 256;
#pragma unroll
        for (int k = 0; k < 8; ++k) Qf[k] = ldh8(q + k * 32 + 8 * g);
    }
    f32x4 O[16];
#pragma unroll
    for (int i = 0; i < 16; ++i) O[i] = {0.f, 0.f, 0.f, 0.f};
    float m = -1e30f, l = 0.f;

    const char* Fb  = (const char*)(F + (size_t)b * 4096 * 256);
    const char* Hbb = (const char*)(Hb + (size_t)b * 256 * 4096);

    int ksrc[4], vsrc[4];
#pragma unroll
    for (int t = 0; t < 4; ++t) {
        int d = (w * 4 + t) * 1024 + lane * 16;
        int row = d >> 9, col = d & 511;
        ksrc[t] = row * 512 + (col ^ ((row & 7) << 4));
        int r128 = d >> 7, wn = d & 127;
        int wp = wn ^ ((r128 & 7) << 4);
        vsrc[t] = ((r128 * 2 + (wp >> 6)) << 13) + (wp & 63);
    }

#define STAGE(bufn, I0)                                                         \
    do {                                                                        \
        const char* kb_ = Fb + (size_t)(I0) * 512;                              \
        const char* vb_ = Hbb + (size_t)(I0) * 2;                               \
        char* kl = (char*)Kd[bufn];                                             \
        char* vl = (char*)Vd[bufn];                                             \
        _Pragma("unroll") for (int t = 0; t < 4; ++t)                           \
            gload16(kb_ + ksrc[t], kl + (w * 4 + t) * 1024);                    \
        _Pragma("unroll") for (int t = 0; t < 4; ++t)                           \
            gload16(vb_ + vsrc[t], vl + (w * 4 + t) * 1024);                    \
    } while (0)

    int i0beg = ks * 2048;
    STAGE(0, i0beg);   // prologue
    __syncthreads();   // drains vmcnt(0): tile 0 ready

    for (int it = 0; it < 64; ++it) {
        int cur = it & 1;
        if (it + 1 < 64) STAGE(cur ^ 1, i0beg + (it + 1) * 32);

        const char* Kl = (const char*)Kd[cur];
        const char* Vb = (const char*)Vd[cur] + vlc;

        f32x4 s0 = {0.f, 0.f, 0.f, 0.f};
        f32x4 s1 = {0.f, 0.f, 0.f, 0.f};
        __builtin_amdgcn_s_setprio(1);
        {
            const char* kr = Kl + r * 512;
            int sw = (r & 7) << 4;
#pragma unroll
            for (int k = 0; k < 8; ++k) {
                f16x8 ka = *reinterpret_cast<const f16x8*>(kr + ((k * 64 + 16 * g) ^ sw));
                s0 = MFMA16(ka, Qf[k], s0);
            }
        }
        {
            const char* kr = Kl + (16 + r) * 512;
            int sw = (r & 7) << 4;
#pragma unroll
            for (int k = 0; k < 8; ++k) {
                f16x8 ka = *reinterpret_cast<const f16x8*>(kr + ((k * 64 + 16 * g) ^ sw));
                s1 = MFMA16(ka, Qf[k], s1);
            }
        }
        __builtin_amdgcn_s_setprio(0);

        float v = fmaxf(fmaxf(fmaxf(s0[0], s0[1]), fmaxf(s0[2], s0[3])),
                        fmaxf(fmaxf(s1[0], s1[1]), fmaxf(s1[2], s1[3])));
        if (!__all(v - m <= 8.0f)) {  // rare: full per-query max + rescale
            v = fmaxf(v, __shfl_xor(v, 16));
            v = fmaxf(v, __shfl_xor(v, 32));
            float mn = fmaxf(m, v);
            float corr = exp2f((m - mn) * L2E);
            m = mn;
            l *= corr;
#pragma unroll
            for (int ct = 0; ct < 16; ++ct) O[ct] *= corr;
        }
#pragma unroll
        for (int q = 0; q < 4; ++q) {
            s0[q] = exp2f((s0[q] - m) * L2E);
            s1[q] = exp2f((s1[q] - m) * L2E);
        }
        l += (s0[0] + s0[1] + s0[2] + s0[3]) + (s1[0] + s1[1] + s1[2] + s1[3]);

        union { u32 wd[4]; f16x8 fr; } pu;
        pu.wd[0] = cvtpk(s0[0], s0[1]);
        pu.wd[1] = cvtpk(s0[2], s0[3]);
        pu.wd[2] = cvtpk(s1[0], s1[1]);
        pu.wd[3] = cvtpk(s1[2], s1[3]);

        __builtin_amdgcn_s_setprio(1);
#pragma unroll
        for (int ct = 0; ct < 16; ++ct) {
            f16x8 vb = *reinterpret_cast<const f16x8*>(Vb + ct * 1024);
            O[ct] = MFMA16(vb, pu.fr, O[ct]);
        }
        __builtin_amdgcn_s_setprio(0);

        __syncthreads();
    }
#undef STAGE

    l += __shfl_xor(l, 16);
    l += __shfl_xor(l, 32);
    float inv = 1.f / l;
    size_t mrow = (size_t)ks * 16384 + b * 4096 + j0 + r;
#pragma unroll
    for (int ct = 0; ct < 16; ++ct) {
        short4v pk;
#pragma unroll
        for (int q = 0; q < 4; ++q) pk[q] = (short)h16(O[ct][q] * inv);
        *reinterpret_cast<short4v*>(OP + mrow * 256 + ct * 16 + 4 * g) = pk;
    }
    if (g == 0) {
        size_t mi = mrow * 2;
        ML[mi] = m;
        ML[mi + 1] = l;
    }
}

// ---------------- final conv, merge fused: blend both OP splits into B-frag ----------------
__global__ __launch_bounds__(256) void k_conv_out(
    const u16* __restrict__ WV, const u16* __restrict__ OP,
    const float* __restrict__ ML, const float* __restrict__ bv,
    float* __restrict__ out) {
    int bidn = blockIdx.x & 255, bido = blockIdx.x >> 8;
    int w = threadIdx.x >> 6, lane = threadIdx.x & 63, r = lane & 15, g = lane >> 4;
    int o0 = bido * 64 + w * 16, n0 = bidn * 64;
    const float L2E = 1.4426950408889634f;
    float wl0[4], wl1[4];
    int nfs[4];
#pragma unroll
    for (int ntl = 0; ntl < 4; ++ntl) {
        int nf = n0 + ntl * 16 + r;
        nfs[ntl] = nf;
        float m0_ = ML[(size_t)nf * 2], l0_ = ML[(size_t)nf * 2 + 1];
        float m1_ = ML[((size_t)16384 + nf) * 2], l1_ = ML[((size_t)16384 + nf) * 2 + 1];
        float M_ = fmaxf(m0_, m1_);
        float a0 = exp2f((m0_ - M_) * L2E) * l0_;
        float a1 = exp2f((m1_ - M_) * L2E) * l1_;
        float inv = 1.f / (a0 + a1);
        wl0[ntl] = a0 * inv;
        wl1[ntl] = a1 * inv;
    }
    f32x4 acc[4];
#pragma unroll
    for (int i = 0; i < 4; ++i) acc[i] = {0.f, 0.f, 0.f, 0.f};
    const u16* arow = WV + (size_t)(o0 + r) * 256;
#pragma unroll
    for (int ks = 0; ks < 8; ++ks) {
        int k0 = ks * 32 + 8 * g;
        f16x8 a = ldh8(arow + k0);
#pragma unroll
        for (int ntl = 0; ntl < 4; ++ntl) {
            f16x8 v0 = ldh8(OP + (size_t)nfs[ntl] * 256 + k0);
            f16x8 v1 = ldh8(OP + ((size_t)16384 + nfs[ntl]) * 256 + k0);
            union { u32 wd[4]; f16x8 fr; } bb;
#pragma unroll
            for (int j = 0; j < 4; ++j) {
                float e0 = wl0[ntl] * (float)v0[2 * j] + wl1[ntl] * (float)v1[2 * j];
                float e1 = wl0[ntl] * (float)v0[2 * j + 1] + wl1[ntl] * (float)v1[2 * j + 1];
                bb.wd[j] = cvtpk(e0, e1);
            }
            acc[ntl] = MFMA16(a, bb.fr, acc[ntl]);
        }
    }
#pragma unroll
    for (int ntl = 0; ntl < 4; ++ntl) {
#pragma unroll
        for (int q = 0; q < 4; ++q) {
            int o = o0 + 4 * g + q;
            int nf = nfs[ntl];
            int bb2 = nf >> 12, n = nf & 4095;
            out[((size_t)(bb2 * 256 + o)) * 4096 + n] = acc[ntl][q] + bv[o];
        }
    }
}

extern "C" void kernel_launch(void* const* d_in, const int* in_sizes, int n_in,
                              void* d_out, int out_size, void* d_ws, size_t ws_size,
                              hipStream_t stream) {
    const float* x  = (const float*)d_in[0];
    const float* Wf = (const float*)d_in[1];
    const float* bf = (const float*)d_in[2];  // cancels in softmax (const in i)
    const float* Wg = (const float*)d_in[3];
    const float* bg = (const float*)d_in[4];
    const float* Wh = (const float*)d_in[5];
    const float* bh = (const float*)d_in[6];
    const float* Wv = (const float*)d_in[7];
    const float* bv = (const float*)d_in[8];
    float* out = (float*)d_out;
    char* ws = (char*)d_ws;
    (void)bf;

    u16* WH = (u16*)(ws + OFF_WH);
    u16* WV = (u16*)(ws + OFF_WV);
    float* MB = (float*)(ws + OFF_MB);
    float* ML = (float*)(ws + OFF_ML);
    u16* M  = (u16*)(ws + OFF_M);
    u16* U  = (u16*)(ws + OFF_U);
    u16* H  = (u16*)(ws + OFF_H);
    u16* XT = (u16*)(ws + OFF_XT);
    u16* OP = (u16*)(ws + OFF_OP);

    k_gemm_M<<<256, 256, 0, stream>>>(Wf, Wg, bg, Wh, Wv, M, MB, WH, WV);
    k_prep<<<256, 256, 0, stream>>>(x, M, MB, WH, bh, XT, U, H);
    k_attn<<<512, 256, 0, stream>>>(XT, U, H, OP, ML);  // K = Xt, Q = U
    k_conv_out<<<1024, 256, 0, stream>>>(WV, OP, ML, bv, out);
}